// Round 17
// baseline (247.504 us; speedup 1.0000x reference)
//
#include <hip/hip_runtime.h>
#include <hip/hip_bf16.h>

using bf16 = __hip_bfloat16;

typedef __bf16 bf16x8 __attribute__((ext_vector_type(8)));
typedef __bf16 bf16x2v __attribute__((ext_vector_type(2)));
typedef float  f32x4  __attribute__((ext_vector_type(4)));
typedef float  f32x16 __attribute__((ext_vector_type(16)));

#define QK_SCALE 0.125f  // 64^-0.5

// ---- async global->LDS, 16B per lane (wave-uniform base + lane*16 on LDS side) ----
__device__ __forceinline__ void load_lds16(const bf16* g, bf16* l) {
  __builtin_amdgcn_global_load_lds(
      (const __attribute__((address_space(1))) unsigned int*)g,
      (__attribute__((address_space(3))) unsigned int*)l, 16, 0, 0);
}

// ---- pack two fp32 -> bf16x2 in one 32-bit reg (RNE per __bf16 cvt) ----
__device__ __forceinline__ unsigned pack_bf2(float a, float b) {
  bf16x2v v;
  v[0] = (__bf16)a;
  v[1] = (__bf16)b;
  return __builtin_bit_cast(unsigned, v);
}

struct alignas(8) bf16x4s { bf16 a, b, c, d; };

// =====================================================================================
// Merged prep: x fp32->bf16 convert + 3 weight transposes in ONE launch.
//   bid [0,1024)    : Wq^T   | bid [1024,3072) : Wkv^T | bid [3072,4096) : Wo^T
//   bid [4096,8192) : x -> bf16
// =====================================================================================
__global__ __launch_bounds__(256)
void prep_k(const float* __restrict__ x, bf16x4s* __restrict__ xb,
            const float* __restrict__ Wq, const float* __restrict__ Wkv,
            const float* __restrict__ Wo,
            bf16* __restrict__ WT, bf16* __restrict__ WoT)
{
  const int bid = blockIdx.x;
  const int tid = threadIdx.x;

  if (bid >= 4096) {
    const int i = (bid - 4096) * 256 + tid;
    const float4 v = ((const float4*)x)[i];
    xb[i] = { (bf16)v.x, (bf16)v.y, (bf16)v.z, (bf16)v.w };
    return;
  }

  __shared__ bf16 t[32][33];
  const float* in;
  bf16* out;
  int ldi, c0, r0;
  if (bid < 1024)      { in = Wq;  out = WT;           ldi = 1024;
                         c0 = (bid & 31) * 32;        r0 = (bid >> 5) * 32; }
  else if (bid < 3072) { const int lb = bid - 1024;
                         in = Wkv; out = WT + 1048576; ldi = 2048;
                         c0 = (lb % 64) * 32;          r0 = (lb / 64) * 32; }
  else                 { const int lb = bid - 3072;
                         in = Wo;  out = WoT;          ldi = 1024;
                         c0 = (lb & 31) * 32;          r0 = (lb >> 5) * 32; }
  const int xx = tid & 31, yy = tid >> 5;
#pragma unroll
  for (int dy = 0; dy < 32; dy += 8)
    t[yy + dy][xx] = (bf16)in[(long)(r0 + yy + dy) * ldi + c0 + xx];
  __syncthreads();
#pragma unroll
  for (int dy = 0; dy < 32; dy += 8)
    out[(long)(c0 + yy + dy) * 1024 + r0 + xx] = t[xx][yy + dy];
}

// =====================================================================================
// Shared GEMM body, double-buffered staging (qk_j-verified single-sync pattern).
// =====================================================================================
template<int TM, int TN, int WM, int WN, bool BIAS, typename CT>
__device__ __forceinline__
void gemm_body(char* smem, const bf16* __restrict__ A, const bf16* __restrict__ B,
               CT* __restrict__ C, const float* __restrict__ bias,
               int K, int lda, int ldb, int ldc, int tm0, int tn0, float alpha)
{
  constexpr int BK = 64;
  constexpr int LDE = TN + 8;
  constexpr int HALF = (TM + TN) * BK;
  bf16* ls0 = (bf16*)smem;            // [A0 | B0]
  bf16* ls1 = ls0 + HALF;             // [A1 | B1]

  const int tid = threadIdx.x;
  const int w = tid >> 6, l = tid & 63;
  constexpr int WCOLS = TN / WN;
  const int wm = (w / WCOLS) * WM, wn = (w % WCOLS) * WN;
  constexpr int AM = WM / 16, AN = WN / 16;
  f32x4 acc[AM][AN] = {};
  const int kg = l >> 4, rl = l & 15;

  constexpr int RA = TM / 32, RB = TN / 32;   // 32 rows per 256-thread staging pass
  const int srow0 = tid >> 3;                  // 8 x 16B chunks per 64-col row
  const int schunk = tid & 7;

  auto stage = [&](int k0, bf16* dst) {
    bf16* dA = dst;
    bf16* dB = dst + TM * BK;
#pragma unroll
    for (int r = 0; r < RA; ++r) {
      const int row = r * 32 + srow0;
      const int sw = ((row >> 1) & 7) ^ ((row & 1) << 2);
      const int col8 = schunk ^ sw;
      load_lds16(A + (long)(tm0 + row) * lda + (k0 + col8 * 8),
                 &dA[row * BK + schunk * 8]);
    }
#pragma unroll
    for (int r = 0; r < RB; ++r) {
      const int row = r * 32 + srow0;
      const int sw = ((row >> 1) & 7) ^ ((row & 1) << 2);
      const int col8 = schunk ^ sw;
      load_lds16(B + (long)(tn0 + row) * ldb + (k0 + col8 * 8),
                 &dB[row * BK + schunk * 8]);
    }
  };

  const int NT = K / BK;
  stage(0, ls0);
  __syncthreads();   // buf0 landed

  for (int kt = 0; kt < NT; ++kt) {
    if (kt + 1 < NT) stage((kt + 1) * BK, (kt & 1) ? ls0 : ls1);   // fire-and-forget
    const bf16* lsA = (kt & 1) ? ls1 : ls0;
    const bf16* lsB = lsA + TM * BK;

#pragma unroll
    for (int half = 0; half < 2; ++half) {
      bf16x8 af[AM], bfr[AN];
#pragma unroll
      for (int i = 0; i < AM; ++i) {
        const int m = wm + i * 16 + rl;
        const int sw = ((m >> 1) & 7) ^ ((m & 1) << 2);
        const int p = (half * 4 + kg) ^ sw;
        af[i] = *(const bf16x8*)&lsA[m * BK + p * 8];
      }
#pragma unroll
      for (int j = 0; j < AN; ++j) {
        const int n = wn + j * 16 + rl;
        const int sw = ((n >> 1) & 7) ^ ((n & 1) << 2);
        const int p = (half * 4 + kg) ^ sw;
        bfr[j] = *(const bf16x8*)&lsB[n * BK + p * 8];
      }
#pragma unroll
      for (int i = 0; i < AM; ++i)
#pragma unroll
        for (int j = 0; j < AN; ++j)
          acc[i][j] = __builtin_amdgcn_mfma_f32_16x16x32_bf16(af[i], bfr[j], acc[i][j], 0, 0, 0);
    }
    __syncthreads();   // releases buf[kt&1]; guarantees buf[(kt+1)&1] landed
  }

  if constexpr (sizeof(CT) == 2) {
    bf16* ep = (bf16*)smem;
#pragma unroll
    for (int i = 0; i < AM; ++i) {
#pragma unroll
      for (int j = 0; j < AN; ++j) {
        const int col = wn + j * 16 + rl;
        float bv = 0.f;
        if (BIAS) bv = bias[tn0 + col];
#pragma unroll
        for (int v = 0; v < 4; ++v) {
          const int row = wm + i * 16 + (l >> 4) * 4 + v;
          ep[row * LDE + col] = (bf16)(acc[i][j][v] * alpha + bv);
        }
      }
    }
    __syncthreads();
    constexpr int CH = (TM * TN) / 2048;
#pragma unroll
    for (int c = 0; c < CH; ++c) {
      const int gidx = (c * 256 + tid) * 8;
      const int row = gidx / TN, col = gidx % TN;
      *(uint4*)&C[(long)(tm0 + row) * ldc + tn0 + col] = *(const uint4*)&ep[row * LDE + col];
    }
    __syncthreads();   // safe for callers looping the body
  } else {
#pragma unroll
    for (int i = 0; i < AM; ++i) {
#pragma unroll
      for (int j = 0; j < AN; ++j) {
        const int col = tn0 + wn + j * 16 + rl;
        float bv = 0.f;
        if (BIAS) bv = bias[col];
#pragma unroll
        for (int v = 0; v < 4; ++v) {
          const int row = tm0 + wm + i * 16 + (l >> 4) * 4 + v;
          C[(long)row * ldc + col] = (CT)(acc[i][j][v] * alpha + bv);
        }
      }
    }
  }
}

// =====================================================================================
// Generic NT GEMM kernel (thin wrapper over gemm_body; used for PV and out GEMMs).
// =====================================================================================
template<int TM, int TN, int WM, int WN, bool BIAS, typename CT>
__global__ __launch_bounds__(256, 2)
void gemm_nt(const bf16* __restrict__ A, const bf16* __restrict__ B,
             CT* __restrict__ C, const float* __restrict__ bias,
             int K, int lda, int ldb, int ldc,
             long sA0, long sA1, long sB0, long sB1, long sC0, long sC1,
             int nz1, float alpha)
{
  constexpr int BK = 64;
  constexpr int LDE = TN + 8;
  constexpr unsigned SB_STAGE = (TM + TN) * BK * 2 * 2;   // double-buffered
  constexpr unsigned SB_EP = (sizeof(CT) == 2) ? TM * LDE * 2 : 0;
  constexpr unsigned SBYTES = SB_STAGE > SB_EP ? SB_STAGE : SB_EP;
  __shared__ __align__(16) char smem[SBYTES];

  const int z = blockIdx.z;
  A += (long)(z / nz1) * sA0 + (long)(z % nz1) * sA1;
  B += (long)(z / nz1) * sB0 + (long)(z % nz1) * sB1;
  C += (long)(z / nz1) * sC0 + (long)(z % nz1) * sC1;
  gemm_body<TM, TN, WM, WN, BIAS, CT>(smem, A, B, C, bias, K, lda, ldb, ldc,
                                      blockIdx.y * TM, blockIdx.x * TN, alpha);
}

// =====================================================================================
// Merged proj + V^T dispatcher (128x128 proj tile, dbuf 64 KB).
//   bid [0,512)    : proj QKV[:,0..2048) = xb @ [Wq|Wkv_K]^T  (16 x-tiles, 32 y-tiles)
//   bid [512,1024) : VT[b,G] = WkvT_V[G] @ xb_b^T             (8 x-tiles, 64 z)
// =====================================================================================
__global__ __launch_bounds__(256, 2)
void projvt_k(const bf16* __restrict__ xb, const bf16* __restrict__ WT,
              bf16* __restrict__ QKV, bf16* __restrict__ VT)
{
  __shared__ __align__(16) char smem[65536];   // proj dbuf (128+128)*64*2*2 = 64 KB
  const int bid = blockIdx.x;
  if (bid < 512) {
    gemm_body<128, 128, 64, 64, false, bf16>(smem, xb, WT, QKV, nullptr,
        1024, 1024, 1024, 3072, (bid >> 4) * 128, (bid & 15) * 128, 1.f);
  } else {
    const int lb = bid - 512;
    const int xt = lb & 7, z = lb >> 3;        // z = b*16 + gp
    const int b2 = z >> 4, gp = z & 15;
    gemm_body<64, 128, 32, 64, false, bf16>(smem,
        WT + 2097152 + (long)gp * 65536,
        xb + (long)b2 * 1048576,
        VT + (long)b2 * 1048576 + (long)gp * 65536, nullptr,
        1024, 1024, 1024, 1024, 0, xt * 128, 1.f);
  }
}

// =====================================================================================
// QK^T, A-resident j-loop, double-buffered K staging (round-14-verified).
// =====================================================================================
__global__ __launch_bounds__(256, 2)
void qk_j(const bf16* __restrict__ QKV, bf16* __restrict__ S)
{
  constexpr int BK = 64;
  __shared__ __align__(16) bf16 lsA[128 * BK];
  __shared__ __align__(16) bf16 lsB[2][128 * BK];
  const int z = blockIdx.z;                   // b*16 + h
  const int b = z >> 4, h = z & 15;
  const bf16* Q  = QKV + (long)b * 3145728 + h * 64;          // rows i, lda=3072
  const bf16* Kp = QKV + (long)b * 3145728 + 1024 + h * 64;   // rows j, ldb=3072
  bf16* C = S + (long)z * 1048576;                             // [1024][1024]
  const int tm0 = blockIdx.x * 128;

  const int tid = threadIdx.x;
  const int w = tid >> 6, l = tid & 63;
  const int wm = (w >> 1) * 64, wn = (w & 1) * 64;   // 2x2 waves on 128x128
  const int kg = l >> 4, rl = l & 15;
  const int srow0 = tid >> 3, schunk = tid & 7;

  // stage A (Q-tile) once + B(0) into lsB[0]
#pragma unroll
  for (int r = 0; r < 4; ++r) {
    const int row = r * 32 + srow0;
    const int sw = ((row >> 1) & 7) ^ ((row & 1) << 2);
    const int col8 = schunk ^ sw;
    load_lds16(Q + (long)(tm0 + row) * 3072 + col8 * 8, &lsA[row * BK + schunk * 8]);
  }
#pragma unroll
  for (int r = 0; r < 4; ++r) {
    const int row = r * 32 + srow0;
    const int sw = ((row >> 1) & 7) ^ ((row & 1) << 2);
    const int col8 = schunk ^ sw;
    load_lds16(Kp + (long)row * 3072 + col8 * 8, &lsB[0][row * BK + schunk * 8]);
  }
  __syncthreads();   // A and B(0) landed (vmcnt drained)

  for (int t = 0; t < 8; ++t) {
    // prefetch B(t+1) into the other buffer; hides under compute+store of tile t
    if (t < 7) {
#pragma unroll
      for (int r = 0; r < 4; ++r) {
        const int row = r * 32 + srow0;
        const int sw = ((row >> 1) & 7) ^ ((row & 1) << 2);
        const int col8 = schunk ^ sw;
        load_lds16(Kp + (long)((t + 1) * 128 + row) * 3072 + col8 * 8,
                   &lsB[(t + 1) & 1][row * BK + schunk * 8]);
      }
    }

    const bf16* bcur = lsB[t & 1];
    f32x4 acc[4][4] = {};
#pragma unroll
    for (int half = 0; half < 2; ++half) {
      bf16x8 af[4], bfr[4];
#pragma unroll
      for (int i = 0; i < 4; ++i) {
        const int m = wm + i * 16 + rl;
        const int sw = ((m >> 1) & 7) ^ ((m & 1) << 2);
        const int p = (half * 4 + kg) ^ sw;
        af[i] = *(const bf16x8*)&lsA[m * BK + p * 8];
      }
#pragma unroll
      for (int j = 0; j < 4; ++j) {
        const int n = wn + j * 16 + rl;
        const int sw = ((n >> 1) & 7) ^ ((n & 1) << 2);
        const int p = (half * 4 + kg) ^ sw;
        bfr[j] = *(const bf16x8*)&bcur[n * BK + p * 8];
      }
#pragma unroll
      for (int i = 0; i < 4; ++i)
#pragma unroll
        for (int j = 0; j < 4; ++j)
          acc[i][j] = __builtin_amdgcn_mfma_f32_16x16x32_bf16(af[i], bfr[j], acc[i][j], 0, 0, 0);
    }

    // direct scaled stores (bitwise == LDS-epilogue values)
    const int tn0 = t * 128;
#pragma unroll
    for (int i = 0; i < 4; ++i)
#pragma unroll
      for (int j = 0; j < 4; ++j) {
        const int col = tn0 + wn + j * 16 + rl;
#pragma unroll
        for (int v = 0; v < 4; ++v) {
          const int row = tm0 + wm + i * 16 + kg * 4 + v;
          C[(long)row * 1024 + col] = (bf16)(acc[i][j][v] * QK_SCALE);
        }
      }
    __syncthreads();   // releases buf[t&1]; guarantees buf[(t+1)&1] landed
  }
}

// =====================================================================================
// Fused talking-heads middle, MFMA version V5 (R17): premix/postmix upgraded from
// 2x 16x16x32 (half-K zeroed + hi/lo double-MFMA = 4 MFMA-equiv per useful op) to ONE
// 32x32x16 per 32-col chunk with hi coeffs in A-rows 0-15 and lo residuals in rows
// 16-31 (the rounds-1..6-verified formulation: output pairs d[k]+d[k+8], G-map
// k+(k&4)+4H, cross-half shfl_xor(.,32) exchange, /Z folded into A').
// Per thread vs V4: MFMA cycles -60% (64x5 -> 16x8), LDS b32 reads halved (64->32,
// still <=2-way: row offset 4*LDJ == 16 mod 32 banks), shuffles 64->16, postmix
// stores become full 64B lines (32 lanes x 2B contiguous per k).
// Staging, Z topology (5-step half-wave butterfly + redZ), grid unchanged.
// =====================================================================================
__global__ __launch_bounds__(256)
void mix_softmax_mix(bf16* __restrict__ S,
                     const float* __restrict__ mixpre, const float* __restrict__ mixpost)
{
  constexpr int LDJ = 1028;                            // dwords/row; 4*LDJ % 32 == 16
  __shared__ __align__(16) unsigned int lSp[8 * LDJ];  // h-pair packed S (32.9 KB)
  __shared__ float pre[256], post[256];
  __shared__ float redZ[4][16];
  const int i = blockIdx.x, b = blockIdx.y;
  const int tid = threadIdx.x;
  pre[tid]  = mixpre[tid];
  post[tid] = mixpost[tid];
  const long hstr = 1048576L;
  bf16* Srow = S + (long)b * 16 * hstr + (long)i * 1024;
  const int w = tid >> 6, l = tid & 63;
  const int col = l & 31;          // 32x32 op column
  const int H = l >> 5;            // k-half: k = H*8 + e
  const int g16 = l & 15;
  const bool loRow = (l & 16) != 0;

  // stage: one uint4 per thread per iter (4 cols, h-pair packed), conflict-free writes
#pragma unroll
  for (int r = 0; r < 8; ++r) {
    const int v = r * 256 + tid;
    const int h2 = v >> 8, jw = (v & 255) * 4;   // row-pair, word (=column) offset
    const uint2 a  = *(const uint2*)&Srow[(long)(2 * h2)     * hstr + jw];
    const uint2 c2 = *(const uint2*)&Srow[(long)(2 * h2 + 1) * hstr + jw];
    uint4 w0;
    w0.x = (a.x & 0xFFFFu) | (c2.x << 16);
    w0.y = (a.x >> 16)     | (c2.x & 0xFFFF0000u);
    w0.z = (a.y & 0xFFFFu) | (c2.y << 16);
    w0.w = (a.y >> 16)     | (c2.y & 0xFFFF0000u);
    *(uint4*)&lSp[h2 * LDJ + jw] = w0;
  }
  __syncthreads();

  // premix A-frag (32x32x16): rows 0-15 hi coeffs, rows 16-31 lo residuals; k=H*8+e
  bf16x8 aPre;
#pragma unroll
  for (int e = 0; e < 8; ++e) {
    const int hh = H * 8 + e;
    const float c = pre[hh * 16 + g16];
    const __bf16 hi = (__bf16)c;
    aPre[e] = loRow ? (__bf16)(c - (float)hi) : hi;
  }

  const int cw = w * 256;          // wave-exclusive 256-column span (8 chunks of 32)

  // ---- premix MFMA + exp; p-hat packed into registers; Z partials ----
  unsigned pk[8][4];               // p-hat per chunk: {g0g1, g2g3, g4g5, g6g7}+4H set
  float zac[8];
#pragma unroll
  for (int k = 0; k < 8; ++k) zac[k] = 0.f;
#pragma unroll
  for (int c = 0; c < 8; ++c) {
    const int col32 = cw + c * 32 + col;
    uint4 bw;
    bw.x = lSp[(H * 4 + 0) * LDJ + col32];
    bw.y = lSp[(H * 4 + 1) * LDJ + col32];
    bw.z = lSp[(H * 4 + 2) * LDJ + col32];
    bw.w = lSp[(H * 4 + 3) * LDJ + col32];
    const bf16x8 bfr = __builtin_bit_cast(bf16x8, bw);  // h = H*8 .. H*8+7
    f32x16 d = {};
    d = __builtin_amdgcn_mfma_f32_32x32x16_bf16(aPre, bfr, d, 0, 0, 0);
    float ev[8];
#pragma unroll
    for (int k = 0; k < 8; ++k) {
      ev[k] = __expf(d[k] + d[k + 8] - 10.f);   // hi row g + lo row g+16 pair
      zac[k] += ev[k];
    }
    pk[c][0] = pack_bf2(ev[0], ev[1]);
    pk[c][1] = pack_bf2(ev[2], ev[3]);
    pk[c][2] = pack_bf2(ev[4], ev[5]);
    pk[c][3] = pack_bf2(ev[6], ev[7]);
  }
  // Z reduce over the 32 cols of each half (same g-set lanes), then cross-wave partials
#pragma unroll
  for (int off = 1; off < 32; off <<= 1) {
#pragma unroll
    for (int k = 0; k < 8; ++k) zac[k] += __shfl_xor(zac[k], off, 64);
  }
  if ((l & 31) == 0) {
#pragma unroll
    for (int k = 0; k < 8; ++k)
      redZ[w][(k & 3) + 8 * (k >> 2) + 4 * H] = zac[k];
  }
  __syncthreads();

  // postmix A'-frag: A'[G(=row)][k=g] = post[g,G]/Z_g, hi/lo rows
  bf16x8 aPost;
#pragma unroll
  for (int e = 0; e < 8; ++e) {
    const int g = H * 8 + e;
    const float Z = redZ[0][g] + redZ[1][g] + redZ[2][g] + redZ[3][g];
    const float c = post[g * 16 + g16] / Z;
    const __bf16 hi = (__bf16)c;
    aPost[e] = loRow ? (__bf16)(c - (float)hi) : hi;
  }

  // ---- postmix: B-frags via cross-half exchange of register p-hat; line stores ----
#pragma unroll
  for (int c = 0; c < 8; ++c) {
    const int col32 = cw + c * 32 + col;
    const unsigned pA = pk[c][0];
    const unsigned pB = pk[c][1];
    const unsigned pC = pk[c][2];
    const unsigned pD = pk[c][3];
    const unsigned x0 = (unsigned)__shfl_xor((int)(H ? pA : pC), 32, 64);
    const unsigned x1 = (unsigned)__shfl_xor((int)(H ? pB : pD), 32, 64);
    uint4 praw;
    praw.x = H ? x0 : pA;
    praw.y = H ? x1 : pB;
    praw.z = H ? pC : x0;
    praw.w = H ? pD : x1;
    const bf16x8 pfr = __builtin_bit_cast(bf16x8, praw);  // g = H*8 .. H*8+7
    f32x16 d2 = {};
    d2 = __builtin_amdgcn_mfma_f32_32x32x16_bf16(aPost, pfr, d2, 0, 0, 0);
#pragma unroll
    for (int k = 0; k < 8; ++k) {
      const int G = k + (k & 4) + (H << 2);   // lane's G-set
      Srow[(long)G * hstr + col32] = (bf16)(d2[k] + d2[k + 8]);
    }
  }
}

// =====================================================================================
extern "C" void kernel_launch(void* const* d_in, const int* in_sizes, int n_in,
                              void* d_out, int out_size, void* d_ws, size_t ws_size,
                              hipStream_t stream)
{
  // All inputs/outputs are FP32 per the reference.
  const float* x     = (const float*)d_in[0];
  const float* Wq    = (const float*)d_in[1];
  const float* Wkv   = (const float*)d_in[2];
  const float* mpre  = (const float*)d_in[3];
  const float* mpost = (const float*)d_in[4];
  const float* Wo    = (const float*)d_in[5];
  const float* bo    = (const float*)d_in[6];
  float* out = (float*)d_out;

  char* ws = (char*)d_ws;
  const size_t MB = 1024 * 1024;
  if (ws_size < 184 * MB) return;
  bf16* xb   = (bf16*)(ws);             // [4096,1024]           8 MB
  bf16* QKV  = (bf16*)(ws + 8 * MB);    // [4096,3072] Q|K       24 MB
  bf16* WT   = (bf16*)(ws + 32 * MB);   // [3072,1024] WqT|WkvT  6 MB
  bf16* WoT  = (bf16*)(ws + 38 * MB);   // [1024,1024]           2 MB
  bf16* VT   = (bf16*)(ws + 40 * MB);   // [4,16,64,1024]        8 MB
  bf16* Obuf = (bf16*)(ws + 48 * MB);   // [4096,1024]           8 MB
  bf16* Sbuf = (bf16*)(ws + 56 * MB);   // [4,16,1024,1024]    128 MB

  // 0+1) merged prep: x convert + 3 weight transposes
  prep_k<<<8192, 256, 0, stream>>>(x, (bf16x4s*)xb, Wq, Wkv, Wo, WT, WoT);

  // 2+3) merged projection (Q|K, 128x128 dbuf) + V^T direct GEMM (dbuf)
  projvt_k<<<1024, 256, 0, stream>>>(xb, WT, QKV, VT);

  // 4) S = SCALE * Q_bh @ K_bh^T  (A-resident j-loop, double-buffered K staging)
  qk_j<<<dim3(8, 1, 64), 256, 0, stream>>>(QKV, Sbuf);

  // 5) fused pre-mix + softmax + post-mix, in place on S (V5: 32x32x16 hi/lo rows)
  mix_softmax_mix<<<dim3(1024, 4, 1), 256, 0, stream>>>(Sbuf, mpre, mpost);

  // 6) O_bG = P_bG @ V_bG  (dbuf body, grid (1,8,64), 512 blocks = 2/CU)
  gemm_nt<128, 64, 64, 32, false, bf16><<<dim3(1, 8, 64), 256, 0, stream>>>(
      Sbuf, VT, Obuf, nullptr, 1024, 1024, 1024, 1024,
      16L * 1048576, 1048576, 16L * 65536, 65536, 1048576, 64, 16, 1.f);

  // 7) out = O @ Wo + bo  (dbuf body, TN=64 tiles -> 512 blocks = 2/CU)
  gemm_nt<128, 64, 64, 32, true, float><<<dim3(16, 32, 1), 256, 0, stream>>>(
      Obuf, WoT, out, bo, 1024, 1024, 1024, 1024, 0, 0, 0, 0, 0, 0, 1, 1.f);
}